// Round 5
// baseline (690.632 us; speedup 1.0000x reference)
//
#include <hip/hip_runtime.h>

#define DIM 256
#define VDIM 300

// ws layout (float offsets)
#define OFF_BASE 0        // 256*256 floats (node embeddings)
#define OFF_CAND 65536    // 4*256 (candidate vectors for node 255)
#define OFF_DS   66560    // 1 (data_score)
#define OFF_R    66624    // 16*256*256 (per-graph r-vectors)

// ---------------- base: emb = data_vecs[data] @ data_w + data_b ----------------
__global__ __launch_bounds__(256) void base_kernel(const int* __restrict__ data,
    const float* __restrict__ data_vecs, const float* __restrict__ data_w,
    const float* __restrict__ data_b, float* __restrict__ ws) {
  __shared__ float s_v[VDIM];
  const int i = blockIdx.x, t = threadIdx.x;
  const int row = data[i];
  for (int k = t; k < VDIM; k += 256) s_v[k] = data_vecs[(size_t)row * VDIM + k];
  __syncthreads();
  float acc = data_b[t];
  for (int k = 0; k < VDIM; ++k) acc = fmaf(s_v[k], data_w[k * DIM + t], acc);
  ws[OFF_BASE + i * DIM + t] = acc;
}

// ---------------- prep: cand vectors + data_score (5 blocks in parallel) -------
__global__ __launch_bounds__(256) void prep_kernel(const float* __restrict__ edge_w,
    const float* __restrict__ edge_b, const float* __restrict__ sdw,
    const float* __restrict__ sdb, float* __restrict__ ws) {
  __shared__ float s_b[DIM];
  __shared__ float s_red[DIM];
  const int e = blockIdx.x, t = threadIdx.x;
  s_b[t] = ws[OFF_BASE + 255 * DIM + t];
  __syncthreads();
  if (e < 4) {
    float acc = edge_b[e * DIM + t];
    for (int d = 0; d < DIM; ++d)
      acc = fmaf(s_b[d], edge_w[(size_t)e * DIM * DIM + d * DIM + t], acc);
    ws[OFF_CAND + e * DIM + t] = acc;
  } else {
    s_red[t] = (s_b[t] + sdb[t]) * sdw[t];
    __syncthreads();
    for (int off = 128; off > 0; off >>= 1) {
      if (t < off) s_red[t] += s_red[t + off];
      __syncthreads();
    }
    if (t == 0) ws[OFF_DS] = s_red[0];
  }
}

// ---------------- per-tile matvec from W-registers (half-row per thread) -------
template <int MT>
__device__ __forceinline__ void tile_compute(const float4 (&w)[32],
    const float* __restrict__ s_rp, float (*__restrict__ s_out)[8][DIM],
    const int kh, const int dd) {
  float acc[MT];
  #pragma unroll
  for (int m = 0; m < MT; ++m) acc[m] = 0.f;
  #pragma unroll
  for (int j = 0; j < 32; ++j) {
    const float4 wv = w[j];
    #pragma unroll
    for (int m = 0; m < MT; ++m) {
      // wave-uniform address -> LDS broadcast, conflict-free
      const float4 rv = *(const float4*)(s_rp + m * DIM + kh * 128 + j * 4);
      acc[m] = fmaf(wv.x, rv.x, acc[m]);
      acc[m] = fmaf(wv.y, rv.y, acc[m]);
      acc[m] = fmaf(wv.z, rv.z, acc[m]);
      acc[m] = fmaf(wv.w, rv.w, acc[m]);
    }
  }
  #pragma unroll
  for (int m = 0; m < MT; ++m) s_out[kh][m][dd] = acc[m];
}

// ---------------- tree: ONE block (512 thr) per graph, zero cross-block sync ---
// 512 thr = (dd 0..255) x (kh 0..1); thread holds W[e][dd][kh*128..+128) in
// 32 float4 = 128 VGPRs. __launch_bounds__(512,2) -> 256-VGPR cap, no spill.
__global__ __launch_bounds__(512, 2) void tree_kernel(
    const int* __restrict__ graphs, const int* __restrict__ edges,
    const float* __restrict__ edge_w, const float* __restrict__ edge_b,
    const float* __restrict__ semb_w, const float* __restrict__ semb_b,
    float* __restrict__ ws, float* __restrict__ out) {
  __shared__ float s_rp[8 * DIM];      // staged parent r-vectors (8 KB)
  __shared__ float s_out[2][8][DIM];   // k-half partials (16 KB)
  __shared__ float s_be[4 * DIM];      // edge biases (4 KB)
  __shared__ float s_red[512];
  __shared__ int s_par[256], s_depth[256], s_edge[256];
  __shared__ int s_list[4 * 256];
  __shared__ int s_cnt[4];
  __shared__ int s_maxd;

  const int t = threadIdx.x;
  const int g = blockIdx.x;
  const int dd = t & 255;   // output dim (W row)
  const int kh = t >> 8;    // k-half 0..1

  const float* base = ws + OFF_BASE;
  const float* candg = ws + OFF_CAND;
  float* rg = ws + OFF_R + (size_t)g * 256 * DIM;

  // ---- setup ----
  if (t == 0) s_maxd = 0;
  if (t < 256) {
    s_par[t] = t + graphs[g * 256 + t];
    s_edge[t] = edges[t];
  }
  for (int idx = t; idx < 4 * DIM; idx += 512) s_be[idx] = edge_b[idx];
  __syncthreads();
  if (t < 256) {
    int dpt = 0, k = t;
    while (k != 0) { k = s_par[k]; ++dpt; }
    s_depth[t] = dpt;
    atomicMax(&s_maxd, dpt);
    rg[t] = semb_w[t];   // r(root) = score_emb_w
  }
  __syncthreads();

  const int maxd = s_maxd;
  float preg = 0.f;

  // ---- level loop (parents of level d are exactly at level d-1) ----
  for (int d = 1; d <= maxd; ++d) {
    if (t < 4) s_cnt[t] = 0;
    __syncthreads();
    if (t > 0 && t < 255 && s_depth[t] == d) {
      const int e = s_edge[t];
      const int p = atomicAdd(&s_cnt[e], 1);
      s_list[e * 256 + p] = t;
    }
    __syncthreads();

    for (int e = 0; e < 4; ++e) {
      const int B = s_cnt[e];
      if (B == 0) continue;
      // W half-row -> 32 float4 registers (line-contiguous per thread)
      float4 w[32];
      {
        const float4* Wp = (const float4*)(edge_w +
            ((size_t)e * DIM + dd) * DIM + kh * 128);
        #pragma unroll
        for (int j = 0; j < 32; ++j) w[j] = Wp[j];
      }
      int mb = 0;
      while (mb < B) {
        const int rem = B - mb;
        const int mt = rem >= 5 ? 8 : (rem >= 3 ? 4 : rem);
        const int mv = (rem < mt) ? rem : mt;
        // stage parent r-vectors (zero-pad)
        for (int idx = t; idx < mt * 64; idx += 512) {
          const int m = idx >> 6, k4 = idx & 63;
          float4 v = make_float4(0.f, 0.f, 0.f, 0.f);
          if (m < mv) {
            const int nd = s_list[e * 256 + mb + m];
            v = *(const float4*)(rg + (size_t)s_par[nd] * DIM + k4 * 4);
          }
          *(float4*)(s_rp + m * DIM + k4 * 4) = v;
        }
        __syncthreads();
        if (mt == 8)      tile_compute<8>(w, s_rp, s_out, kh, dd);
        else if (mt == 4) tile_compute<4>(w, s_rp, s_out, kh, dd);
        else if (mt == 2) tile_compute<2>(w, s_rp, s_out, kh, dd);
        else              tile_compute<1>(w, s_rp, s_out, kh, dd);
        __syncthreads();
        // reduce k-halves, write r_c, accumulate score terms
        for (int idx = t; idx < mv * 256; idx += 512) {
          const int m = idx >> 8, dw = idx & 255;
          const int nd = s_list[e * 256 + mb + m];
          const float val = s_out[0][m][dw] + s_out[1][m][dw];
          rg[(size_t)nd * DIM + dw] = val;
          preg = fmaf(val, base[(size_t)nd * DIM + dw], preg);
          preg = fmaf(s_rp[m * DIM + dw], s_be[e * DIM + dw], preg);
        }
        __syncthreads();
        mb += mt;
      }
    }
  }

  // ---- score_common: root term + block-wide reduce ----
  if (t < 256) preg = fmaf(semb_w[t], base[t] + semb_b[t], preg);
  s_red[t] = preg;
  __syncthreads();
  for (int off = 256; off > 0; off >>= 1) {
    if (t < off) s_red[t] += s_red[t + off];
    __syncthreads();
  }
  const float S = s_red[0] + ws[OFF_DS];
  __syncthreads();

  // ---- 4 candidate dots ----
  const int p255 = s_par[255];
  const float rv255 = (t < 256) ? rg[(size_t)p255 * DIM + t] : 0.f;
  float dots[4];
  for (int e2 = 0; e2 < 4; ++e2) {
    s_red[t] = (t < 256) ? rv255 * candg[e2 * DIM + t] : 0.f;
    __syncthreads();
    for (int off = 256; off > 0; off >>= 1) {
      if (t < off) s_red[t] += s_red[t + off];
      __syncthreads();
    }
    dots[e2] = s_red[0];
    __syncthreads();
  }
  if (t == 0) {
    const int cor = s_edge[255];
    int alts[3]; int na = 0;
    for (int ee = 0; ee < 4; ++ee) if (ee != cor) alts[na++] = ee;
    const int first = (g == 0) ? cor : alts[2];
    out[g * 4 + 0] = S + dots[first];
    out[g * 4 + 1] = S + dots[alts[0]];
    out[g * 4 + 2] = S + dots[alts[1]];
    out[g * 4 + 3] = S + dots[alts[2]];
  }
}

extern "C" void kernel_launch(void* const* d_in, const int* in_sizes, int n_in,
                              void* d_out, int out_size, void* d_ws, size_t ws_size,
                              hipStream_t stream) {
  (void)in_sizes; (void)n_in; (void)out_size; (void)ws_size;
  const int* data        = (const int*)d_in[0];
  const int* edges       = (const int*)d_in[2];
  const int* graphs      = (const int*)d_in[3];
  const float* data_vecs = (const float*)d_in[4];
  const float* data_w    = (const float*)d_in[5];
  const float* data_b    = (const float*)d_in[6];
  const float* edge_w    = (const float*)d_in[7];
  const float* edge_b    = (const float*)d_in[8];
  const float* semb_w    = (const float*)d_in[9];
  const float* semb_b    = (const float*)d_in[10];
  const float* sdw       = (const float*)d_in[11];
  const float* sdb       = (const float*)d_in[12];
  float* ws  = (float*)d_ws;
  float* out = (float*)d_out;

  hipLaunchKernelGGL(base_kernel, dim3(256), dim3(256), 0, stream,
                     data, data_vecs, data_w, data_b, ws);
  hipLaunchKernelGGL(prep_kernel, dim3(5), dim3(256), 0, stream,
                     edge_w, edge_b, sdw, sdb, ws);
  hipLaunchKernelGGL(tree_kernel, dim3(16), dim3(512), 0, stream,
                     graphs, edges, edge_w, edge_b, semb_w, semb_b,
                     ws, out);
}